// Round 5
// baseline (201.022 us; speedup 1.0000x reference)
//
#include <hip/hip_runtime.h>

// RoIAlign multi-level extractor (FPN), matches jax reference:
//   K=1024 rois, C=256, OUT=7, SR=2, levels strides {4,8,16,32}, B=2
//
// v2: two-kernel design.
//   Kernel A (K threads): per-roi metadata (level, batch offset, 14 per-axis
//     sample coords: lo/hi indices, frac, valid) -> d_ws table (128 ints/roi).
//     Exact-fp replication of the reference (no fma contraction, double log2
//     for the level binning step discontinuity) happens ONCE per roi here.
//   Kernel B (K*C*49 threads, 1 thread = 1 output element): 16 corner gathers
//     + bilinear + masked mean. No LDS, no barriers, ~200k waves of TLP.
//     Grid = 49*K blocks of 256 exactly (12544 threads per roi, divisible).
//   Rationale: SR=2,OUT=7 -> 28x28 corner grid == 49 bins * 16 corners (784
//     loads either way); LDS staging dedups nothing (sample spacing > 1px),
//     so direct gather removes all staging overhead and unlocks occupancy.
//   Fallback: if ws_size < K*512 B, launch the verified v1 block-per-roi kernel.

#define CCH 256
#define NS  14   // OUT*SR samples per axis
#define NG  28   // 2*NS corner rows/cols (lo then hi)
#define MSTRIDE 128  // ints per roi in metadata table

// ---------------- Kernel A: per-roi metadata ----------------
__global__ __launch_bounds__(256) void roi_meta_kernel(
    const float* __restrict__ rois, int* __restrict__ meta, int K)
{
  const int k = blockIdx.x * 256 + threadIdx.x;
  if (k >= K) return;

  const float r0 = rois[k*5 + 0];
  const float x1 = rois[k*5 + 1], y1 = rois[k*5 + 2];
  const float x2 = rois[k*5 + 3], y2 = rois[k*5 + 4];

  // level: clip(floor(log2(sqrt(w*h)/56 + 1e-6)), 0, 3); replicate f32
  // op-by-op, log2 via double (matches np.log2 f32 at step boundaries)
  const float scl = __fsqrt_rn(__fmul_rn(__fsub_rn(x2, x1), __fsub_rn(y2, y1)));
  const float tq  = __fadd_rn(__fdiv_rn(scl, 56.0f), 1e-6f);
  const float lg  = (float)log2((double)tq);
  int lvl = (int)floorf(lg);
  lvl = lvl < 0 ? 0 : (lvl > 3 ? 3 : lvl);

  const int   sizeL = 256 >> lvl;               // H == W at this level
  const float ssc   = 1.0f / (float)(4 << lvl); // spatial scale

  int* m = meta + (size_t)k * MSTRIDE;
  float* mf = (float*)m;
  m[0] = lvl;
  m[1] = (int)r0 * CCH * sizeL * sizeL;         // batch offset (elements)

  #pragma unroll
  for (int axis = 0; axis < 2; ++axis) {
    const float c1 = axis ? y1 : x1;
    const float c2 = axis ? y2 : x2;
    const float start = __fsub_rn(__fmul_rn(c1, ssc), 0.5f);
    const float rlen  = __fmul_rn(__fsub_rn(c2, c1), ssc);
    const float bwid  = __fdiv_rn(rlen, 7.0f);
    for (int s = 0; s < NS; ++s) {
      const int bin = s >> 1, i = s & 1;
      const float off = ((float)i + 0.5f) * 0.5f;   // (i+0.5)/SR, exact
      const float g = __fadd_rn(__fadd_rn(start, __fmul_rn((float)bin, bwid)),
                                __fmul_rn(off, bwid));
      const float valid = (g >= -1.0f && g <= (float)sizeL) ? 1.0f : 0.0f;
      float cc = fminf(fmaxf(g, 0.0f), (float)(sizeL - 1));
      const int lo0 = (int)floorf(cc);
      int lo, hi; float frac;
      if (lo0 >= sizeL - 1) { lo = sizeL - 1; hi = sizeL - 1; frac = 0.0f; }
      else                  { lo = lo0; hi = lo0 + 1; frac = cc - (float)lo0; }
      if (axis == 0) {   // x
        m[2 + s]  = lo;  m[16 + s] = hi;
        mf[58 + s] = frac; mf[72 + s] = valid;
      } else {           // y (offsets premultiplied by row stride)
        m[30 + s] = lo * sizeL; m[44 + s] = hi * sizeL;
        mf[86 + s] = frac; mf[100 + s] = valid;
      }
    }
  }
}

// ---------------- Kernel B: 1 thread = 1 output element ----------------
__global__ __launch_bounds__(256) void roi_gather_kernel(
    const float* __restrict__ f0, const float* __restrict__ f1,
    const float* __restrict__ f2, const float* __restrict__ f3,
    const int* __restrict__ meta, float* __restrict__ out)
{
  const int tid = blockIdx.x * 256 + threadIdx.x;
  // tid -> (k, c, bin); 12544 = 256*49 per roi, divisible by 64 -> wave-uniform k
  const int k   = tid / 12544;
  const int rem = tid - k * 12544;
  const int c   = rem / 49;
  const int bin = rem - c * 49;
  const int ph  = bin / 7;
  const int pw  = bin - ph * 7;

  const int* m = meta + (size_t)k * MSTRIDE;
  const float* mf = (const float*)m;
  const int lvl  = m[0];
  const int boff = m[1];
  const float* fp = (lvl == 0) ? f0 : (lvl == 1) ? f1 : (lvl == 2) ? f2 : f3;
  const int sz = 256 >> lvl;
  const float* cp = fp + boff + (size_t)c * (sz * sz);

  float acc = 0.0f;
  #pragma unroll
  for (int i = 0; i < 2; ++i) {
    const int sy = 2 * ph + i;
    const int yol = m[30 + sy], yoh = m[44 + sy];
    const float fy = mf[86 + sy], vy = mf[100 + sy];
    #pragma unroll
    for (int j = 0; j < 2; ++j) {
      const int sx = 2 * pw + j;
      const int xl = m[2 + sx], xh = m[16 + sx];
      const float fx = mf[58 + sx], vx = mf[72 + sx];
      const float g00 = cp[yol + xl];
      const float g01 = cp[yol + xh];
      const float g10 = cp[yoh + xl];
      const float g11 = cp[yoh + xh];
      const float sval = (1.0f - fy) * ((1.0f - fx) * g00 + fx * g01)
                       + fy * ((1.0f - fx) * g10 + fx * g11);
      acc += sval * (vy * vx);
    }
  }
  out[tid] = acc * 0.25f;   // out[k][c][ph][pw] == out[tid] (same linearization)
}

// ---------------- v1 fallback (verified): block per roi ----------------
__global__ __launch_bounds__(256) void roi_extract_kernel(
    const float* __restrict__ f0, const float* __restrict__ f1,
    const float* __restrict__ f2, const float* __restrict__ f3,
    const float* __restrict__ rois, float* __restrict__ out, int K)
{
  const int k = blockIdx.x;
  const int t = threadIdx.x;

  __shared__ int   s_xidx[NG];
  __shared__ int   s_yoff[NG];
  __shared__ float s_fx[NS], s_vx[NS], s_fy[NS], s_vy[NS];
  __shared__ int   s_lvl, s_boff;
  __shared__ float s_grid[8][NG][NG + 1];

  if (t < NG) {
    const float r0 = rois[k*5 + 0];
    const float x1 = rois[k*5 + 1], y1 = rois[k*5 + 2];
    const float x2 = rois[k*5 + 3], y2 = rois[k*5 + 4];
    const float scl = __fsqrt_rn(__fmul_rn(__fsub_rn(x2, x1), __fsub_rn(y2, y1)));
    const float tq  = __fadd_rn(__fdiv_rn(scl, 56.0f), 1e-6f);
    const float lg  = (float)log2((double)tq);
    int lvl = (int)floorf(lg);
    lvl = lvl < 0 ? 0 : (lvl > 3 ? 3 : lvl);
    const int   sizeL = 256 >> lvl;
    const float ssc   = 1.0f / (float)(4 << lvl);
    const int axis = t / NS;
    const int s    = t - axis*NS;
    const float c1 = axis ? y1 : x1;
    const float c2 = axis ? y2 : x2;
    const float start = __fsub_rn(__fmul_rn(c1, ssc), 0.5f);
    const float rlen  = __fmul_rn(__fsub_rn(c2, c1), ssc);
    const float bwid  = __fdiv_rn(rlen, 7.0f);
    const int bin = s >> 1, i = s & 1;
    const float off = ((float)i + 0.5f) * 0.5f;
    const float g = __fadd_rn(__fadd_rn(start, __fmul_rn((float)bin, bwid)),
                              __fmul_rn(off, bwid));
    const float valid = (g >= -1.0f && g <= (float)sizeL) ? 1.0f : 0.0f;
    float cc = fminf(fmaxf(g, 0.0f), (float)(sizeL - 1));
    const int lo0 = (int)floorf(cc);
    int lo, hi; float frac;
    if (lo0 >= sizeL - 1) { lo = sizeL - 1; hi = sizeL - 1; frac = 0.0f; }
    else                  { lo = lo0; hi = lo0 + 1; frac = cc - (float)lo0; }
    if (axis == 0) { s_xidx[s] = lo; s_xidx[NS + s] = hi; s_fx[s] = frac; s_vx[s] = valid; }
    else           { s_yoff[s] = lo * sizeL; s_yoff[NS + s] = hi * sizeL;
                     s_fy[s] = frac; s_vy[s] = valid; }
    if (t == 0) { s_lvl = lvl; s_boff = (int)r0 * CCH * sizeL * sizeL; }
  }
  __syncthreads();

  const int lvl = s_lvl;
  const float* fp = (lvl == 0) ? f0 : (lvl == 1) ? f1 : (lvl == 2) ? f2 : f3;
  const int sz = 256 >> lvl;
  const int HW = sz * sz;
  const float* bp = fp + s_boff;
  const int csub = t >> 5;
  const int lane = t & 31;
  const int xo   = (lane < NG) ? s_xidx[lane] : 0;

  for (int cg = 0; cg < CCH / 8; ++cg) {
    const int c0 = cg * 8;
    const float* cp = bp + (size_t)(c0 + csub) * HW;
    if (lane < NG) {
      #pragma unroll
      for (int r = 0; r < NG; ++r) s_grid[csub][r][lane] = cp[s_yoff[r] + xo];
    }
    __syncthreads();
    for (int o = t; o < 8 * 49; o += 256) {
      const int cs  = o / 49;
      const int bin = o - cs * 49;
      const int ph  = bin / 7, pw = bin - ph * 7;
      float acc = 0.0f;
      #pragma unroll
      for (int i = 0; i < 2; ++i) {
        const int sy = 2 * ph + i;
        const float fy = s_fy[sy], vy = s_vy[sy];
        #pragma unroll
        for (int j = 0; j < 2; ++j) {
          const int sx = 2 * pw + j;
          const float fx = s_fx[sx], vx = s_vx[sx];
          const float g00 = s_grid[cs][sy][sx];
          const float g01 = s_grid[cs][sy][NS + sx];
          const float g10 = s_grid[cs][NS + sy][sx];
          const float g11 = s_grid[cs][NS + sy][NS + sx];
          const float sval = (1.0f - fy) * ((1.0f - fx) * g00 + fx * g01)
                           + fy * ((1.0f - fx) * g10 + fx * g11);
          acc += sval * (vy * vx);
        }
      }
      out[((size_t)k * CCH + c0 + cs) * 49 + bin] = acc * 0.25f;
    }
    __syncthreads();
  }
}

extern "C" void kernel_launch(void* const* d_in, const int* in_sizes, int n_in,
                              void* d_out, int out_size, void* d_ws, size_t ws_size,
                              hipStream_t stream) {
  const float* f0   = (const float*)d_in[0];
  const float* f1   = (const float*)d_in[1];
  const float* f2   = (const float*)d_in[2];
  const float* f3   = (const float*)d_in[3];
  const float* rois = (const float*)d_in[4];
  float* out = (float*)d_out;
  const int K = in_sizes[4] / 5;

  const size_t need = (size_t)K * MSTRIDE * sizeof(int);
  if (ws_size >= need) {
    int* meta = (int*)d_ws;
    hipLaunchKernelGGL(roi_meta_kernel, dim3((K + 255) / 256), dim3(256), 0, stream,
                       rois, meta, K);
    hipLaunchKernelGGL(roi_gather_kernel, dim3(K * 49), dim3(256), 0, stream,
                       f0, f1, f2, f3, meta, out);
  } else {
    hipLaunchKernelGGL(roi_extract_kernel, dim3(K), dim3(256), 0, stream,
                       f0, f1, f2, f3, rois, out, K);
  }
}